// Round 1
// baseline (572.344 us; speedup 1.0000x reference)
//
#include <hip/hip_runtime.h>
#include <cstdint>

#define S_LEN 2048
#define HID   4096
#define NHQ   32
#define NKV   8
#define HD    128
#define QKV_N 6144

typedef float  f32x4 __attribute__((ext_vector_type(4)));
typedef short  s16x8 __attribute__((ext_vector_type(8)));
typedef unsigned short ushort_t;

typedef __attribute__((address_space(3))) void       lds_void;
typedef const __attribute__((address_space(1))) void gbl_void;

__device__ __forceinline__ void gload_lds16(const void* g, void* l) {
  __builtin_amdgcn_global_load_lds((gbl_void*)g, (lds_void*)l, 16, 0, 0);
}

__device__ __forceinline__ short f2bf_bits(float f) {
  union { __bf16 b; short s; } u;
  u.b = (__bf16)f;
  return u.s;
}
__device__ __forceinline__ float bf2f(unsigned short u) {
  union { unsigned int i; float f; } x;
  x.i = ((unsigned int)u) << 16;
  return x.f;
}

__device__ __forceinline__ void cvt8(const float* src, ushort_t* dst, int j) {
  const f32x4* s = (const f32x4*)src;
  f32x4 a = s[j * 2], b = s[j * 2 + 1];
  s16x8 r;
  r[0] = f2bf_bits(a[0]); r[1] = f2bf_bits(a[1]); r[2] = f2bf_bits(a[2]); r[3] = f2bf_bits(a[3]);
  r[4] = f2bf_bits(b[0]); r[5] = f2bf_bits(b[1]); r[6] = f2bf_bits(b[2]); r[7] = f2bf_bits(b[3]);
  *((s16x8*)dst + j) = r;
}

// ---------------- fused cvt: hidden (1048576 vec8) + w_qkv (3145728 vec8) ----------------
__global__ __launch_bounds__(256)
void cvt_hw(const float* __restrict__ h, const float* __restrict__ wq,
            ushort_t* __restrict__ hb, ushort_t* __restrict__ wqb) {
  int i = blockIdx.x * 256 + threadIdx.x;
  if (i < 1048576) cvt8(h, hb, i);
  else             cvt8(wq, wqb, i - 1048576);
}

// ---------------- counted-vmcnt waits (literal-only asm, constexpr dispatch) ----------------
template <int N> __device__ __forceinline__ void wait_vm() {
  if constexpr (N == 8)      asm volatile("s_waitcnt vmcnt(8)" ::: "memory");
  else if constexpr (N == 6) asm volatile("s_waitcnt vmcnt(6)" ::: "memory");
  else if constexpr (N == 4) asm volatile("s_waitcnt vmcnt(4)" ::: "memory");
  else if constexpr (N == 3) asm volatile("s_waitcnt vmcnt(3)" ::: "memory");
  else                       asm volatile("s_waitcnt vmcnt(0)" ::: "memory");
}

// ---------------- ring-pipelined bf16 GEMM, C[M][N] = A[M][K] * B[N][K]^T ----------------
// BMx256 tile, 512 threads = 8 waves (2M x 4N), per-wave BM/2 x 64 output.
// LDS = 4-slot ring, each slot one BK=32 K-slice (A: BM x 32, B: 256 x 32).
// Phase s: stage slice s+3 into slot (s+3)&3 (== slot (s-1)&3, read-complete since the
// previous barrier) -> ds_read frags of slot s&3 -> 32(16) MFMA -> s_waitcnt vmcnt(2*PHL)
// (counted, never 0 in steady state: leaves slices s+2,s+3 in flight so their HBM/L2
// latency hides under ~2 compute phases) -> raw s_barrier.
// Swizzle (both-sides): LDS linear for global_load_lds; global source per-lane permuted
// q=(li&3)^(row&3); fragment read applies the same XOR -> 64-lane read set is a dense
// contiguous 1KB (conflict-free) instead of the 8-way conflict of row-major.
template <int BM, bool OUTF32>
__global__ __launch_bounds__(512, 2)
void gemm_ring(const ushort_t* __restrict__ Ag, const ushort_t* __restrict__ Bg,
               void* __restrict__ Cp, int M, int N, int K) {
  constexpr int ALD = BM / 128;   // A-loads per thread per phase (2 for BM=256, 1 for 128)
  constexpr int PHL = ALD + 2;    // total loads per thread per phase
  constexpr int MF  = BM / 32;    // per-wave M fragments
  __shared__ __align__(16) ushort_t As[4][BM * 32];
  __shared__ __align__(16) ushort_t Bs[4][256 * 32];

  const int t = threadIdx.x;
  const int w = t >> 6, l = t & 63;
  const int n16 = l & 15, quad = l >> 4;
  const int wm = w >> 2, wn = w & 3;
  const int sw = quad ^ (n16 & 3);
  const int m0 = blockIdx.x * BM, n0 = blockIdx.y * 256;

  size_t aoff[ALD]; int aldo[ALD];
#pragma unroll
  for (int n2 = 0; n2 < ALD; n2++) {
    int li = n2 * 512 + t, row = li >> 2, q = (li & 3) ^ (row & 3);
    aoff[n2] = (size_t)(m0 + row) * K + q * 8;
    aldo[n2] = li * 16;
  }
  size_t boff[2]; int bldo[2];
#pragma unroll
  for (int n2 = 0; n2 < 2; n2++) {
    int li = n2 * 512 + t, row = li >> 2, q = (li & 3) ^ (row & 3);
    boff[n2] = (size_t)(n0 + row) * K + q * 8;
    bldo[n2] = li * 16;
  }

  f32x4 acc[MF][4] = {};

  auto stage = [&](int slot, int k0) {
#pragma unroll
    for (int n2 = 0; n2 < ALD; n2++)
      gload_lds16(Ag + aoff[n2] + k0, (char*)&As[slot][0] + aldo[n2]);
#pragma unroll
    for (int n2 = 0; n2 < 2; n2++)
      gload_lds16(Bg + boff[n2] + k0, (char*)&Bs[slot][0] + bldo[n2]);
  };

  auto compute = [&](int slot) {
    const char* Ab = (const char*)&As[slot][0];
    const char* Bb = (const char*)&Bs[slot][0];
    s16x8 af[MF], bfr[4];
#pragma unroll
    for (int mf = 0; mf < MF; mf++)
      af[mf] = *(const s16x8*)(Ab + (wm * (BM / 2) + mf * 16 + n16) * 64 + sw * 16);
#pragma unroll
    for (int nf = 0; nf < 4; nf++)
      bfr[nf] = *(const s16x8*)(Bb + (wn * 64 + nf * 16 + n16) * 64 + sw * 16);
    __builtin_amdgcn_s_setprio(1);
#pragma unroll
    for (int mf = 0; mf < MF; mf++)
#pragma unroll
      for (int nf = 0; nf < 4; nf++)
        acc[mf][nf] = __builtin_amdgcn_mfma_f32_16x16x32_bf16(af[mf], bfr[nf], acc[mf][nf], 0, 0, 0);
    __builtin_amdgcn_s_setprio(0);
  };

  const int NS = K >> 5;  // 128 K-slices
  // Prologue: stage slices 0,1,2; drain slice 0, leave 1,2 (2*PHL loads) in flight.
  stage(0, 0); stage(1, 32); stage(2, 64);
  wait_vm<2 * PHL>();
  __builtin_amdgcn_s_barrier();
  asm volatile("" ::: "memory");

  for (int s = 0; s < NS; ++s) {
    if (s + 3 < NS) stage((s + 3) & 3, (s + 3) << 5);
    compute(s & 3);
    // End-of-phase invariant: slice s+1 drained; slices s+2,s+3 may stay in flight.
    if (s <= NS - 4)      wait_vm<2 * PHL>();
    else if (s == NS - 3) wait_vm<PHL>();
    else if (s == NS - 2) wait_vm<0>();
    if (s != NS - 1) { __builtin_amdgcn_s_barrier(); asm volatile("" ::: "memory"); }
  }

#pragma unroll
  for (int mf = 0; mf < MF; mf++)
#pragma unroll
    for (int nf = 0; nf < 4; nf++)
#pragma unroll
      for (int r = 0; r < 4; r++) {
        int row = m0 + wm * (BM / 2) + mf * 16 + quad * 4 + r;
        int col = n0 + wn * 64 + nf * 16 + n16;
        float v = acc[mf][nf][r];
        if constexpr (OUTF32) ((float*)Cp)[(size_t)row * N + col] = v;
        else ((ushort_t*)Cp)[(size_t)row * N + col] = (ushort_t)f2bf_bits(v);
      }
}

// ---------------- fused mid-pipeline: RoPE scatter + V-transpose + cvt(w_o) ----------------
// blocks [0,2048): rope row s; [2048,2560): v_transpose; [2560,10752): w_o cvt.
__global__ __launch_bounds__(256)
void rope_vt_cvtwo(const ushort_t* __restrict__ qkv, ushort_t* __restrict__ Q,
                   ushort_t* __restrict__ Kc, ushort_t* __restrict__ Vt,
                   const float* __restrict__ wo, ushort_t* __restrict__ wob) {
  __shared__ __align__(16) ushort_t tile[64][72];
  const int b = blockIdx.x;
  const int t = threadIdx.x;
  if (b < 2048) {
    const int s = b;
    const float LN1E4_64 = 0.14391156831212787f;  // ln(10000)/64
    for (int item = t; item < (NHQ + NKV) * 64; item += 256) {
      int head = item >> 6, i = item & 63;
      float f = expf(-(float)i * LN1E4_64);
      float ang = (float)s * f;
      float sn, cs;
      sincosf(ang, &sn, &cs);
      if (head < NHQ) {
        const ushort_t* src = qkv + (size_t)s * QKV_N + head * HD;
        float x1 = bf2f(src[i]), x2 = bf2f(src[64 + i]);
        const float sc = 0.08838834764831845f;  // 1/sqrt(128)
        ushort_t* dst = Q + ((size_t)head * S_LEN + s) * HD;
        dst[i]      = (ushort_t)f2bf_bits((x1 * cs - x2 * sn) * sc);
        dst[64 + i] = (ushort_t)f2bf_bits((x1 * sn + x2 * cs) * sc);
      } else {
        int kv = head - NHQ;
        const ushort_t* src = qkv + (size_t)s * QKV_N + 4096 + kv * HD;
        float x1 = bf2f(src[i]), x2 = bf2f(src[64 + i]);
        ushort_t* dst = Kc + ((size_t)kv * S_LEN + s) * HD;
        dst[i]      = (ushort_t)f2bf_bits(x1 * cs - x2 * sn);
        dst[64 + i] = (ushort_t)f2bf_bits(x1 * sn + x2 * cs);
      }
    }
  } else if (b < 2560) {
    const int bb = b - 2048;
    const int s0 = (bb & 31) * 64;
    const int by = bb >> 5;
    const int kv = by >> 1;
    const int d0 = (by & 1) * 64;
    {
      int r = t >> 2, c = (t & 3) * 16;
      const ushort_t* src = qkv + (size_t)(s0 + r) * QKV_N + 5120 + kv * HD + d0 + c;
      *(s16x8*)&tile[r][c]     = *(const s16x8*)src;
      *(s16x8*)&tile[r][c + 8] = *(const s16x8*)(src + 8);
    }
    __syncthreads();
    {
      int d = t >> 2, sseg = (t & 3) * 16;
      ushort_t* dst = Vt + ((size_t)kv * HD + d0 + d) * S_LEN + s0 + sseg;
      s16x8 o1, o2;
#pragma unroll
      for (int i = 0; i < 8; i++) { o1[i] = tile[sseg + i][d]; o2[i] = tile[sseg + 8 + i][d]; }
      *(s16x8*)dst = o1;
      *(s16x8*)(dst + 8) = o2;
    }
  } else {
    int j = (b - 2560) * 256 + t;  // 2097152 vec8 of w_o
    cvt8(wo, wob, j);
  }
}

// ---------------- Flash attention (round-3 structure, unchanged) ----------------
__global__ __launch_bounds__(256)
void attn_kernel(const ushort_t* __restrict__ Q, const ushort_t* __restrict__ Kc,
                 const ushort_t* __restrict__ Vt, ushort_t* __restrict__ Out) {
  __shared__ __align__(16) ushort_t Ks[2][64 * 128];   // 32 KB
  __shared__ __align__(16) ushort_t Vs[2][128 * 64];   // 32 KB
  __shared__ __align__(16) ushort_t Pl[4][16 * 72];    // 9 KB
  const int bx = blockIdx.x;                            // 0..15
  const int h = blockIdx.y;
  const int t = threadIdx.x, w = t >> 6, l = t & 63;
  const int n16 = l & 15, quad = l >> 4;
  const int kv = h >> 2;
  const ushort_t* Qh = Q  + (size_t)h  * S_LEN * HD;
  const ushort_t* Kh = Kc + (size_t)kv * S_LEN * HD;
  const ushort_t* Vh = Vt + (size_t)kv * HD * S_LEN;

  const int qtA = bx, qtB = 31 - bx;
  const int q0A = qtA * 64 + w * 16, q0B = qtB * 64 + w * 16;
  const int tripsA = qtA + 1;
  const int TOTAL = 33;

  s16x8 qfA[4], qfB[4];
#pragma unroll
  for (int ks = 0; ks < 4; ks++) {
    qfA[ks] = *(const s16x8*)(Qh + (size_t)(q0A + n16) * HD + ks * 32 + quad * 8);
    qfB[ks] = *(const s16x8*)(Qh + (size_t)(q0B + n16) * HD + ks * 32 + quad * 8);
  }

  s16x8 ones;
  {
    short v = (n16 == 0) ? (short)0x3F80 : (short)0;
#pragma unroll
    for (int j = 0; j < 8; j++) ones[j] = v;
  }

  f32x4 o[9] = {};
  float mrun[4] = {-1e30f, -1e30f, -1e30f, -1e30f};

  ushort_t* P = Pl[w];

  auto stage = [&](int k0, int buf) {
#pragma unroll
    for (int c = 0; c < 4; c++) {
      int idx = (c * 4 + w) * 64 + l;
      int row = idx >> 4, sc = idx & 15;
      int dseg = sc ^ (row & 15);
      gload_lds16(Kh + (size_t)(k0 + row) * HD + dseg * 8,
                  (char*)&Ks[buf][0] + (c * 4 + w) * 1024);
    }
#pragma unroll
    for (int c = 0; c < 4; c++) {
      int idx = (c * 4 + w) * 64 + l;
      int row = idx >> 3, sc = idx & 7;
      int ks2 = sc ^ (row & 7);
      gload_lds16(Vh + (size_t)row * S_LEN + k0 + ks2 * 8,
                  (char*)&Vs[buf][0] + (c * 4 + w) * 1024);
    }
  };

  stage(0, 0);

  for (int i = 0; i < TOTAL; i++) {
    const bool isA = (i < tripsA);
    const int kt = isA ? i : i - tripsA;
    const int q0 = isA ? q0A : q0B;
    const int k0 = kt * 64;
    const int buf = i & 1;

    __syncthreads();

    if (i + 1 < TOTAL) {
      const bool nA = (i + 1 < tripsA);
      const int nkt = nA ? (i + 1) : (i + 1 - tripsA);
      stage(nkt * 64, buf ^ 1);
    }

    const ushort_t* KsB = &Ks[buf][0];
    const ushort_t* VsB = &Vs[buf][0];

    f32x4 sacc[4] = {};
#pragma unroll
    for (int ks = 0; ks < 4; ks++) {
      s16x8 qf = isA ? qfA[ks] : qfB[ks];
#pragma unroll
      for (int nt = 0; nt < 4; nt++) {
        int row = nt * 16 + n16;
        s16x8 kf = *(const s16x8*)(KsB + row * 128 + ((ks * 4 + quad) ^ (row & 15)) * 8);
        sacc[nt] = __builtin_amdgcn_mfma_f32_16x16x32_bf16(qf, kf, sacc[nt], 0, 0, 0);
      }
    }

    if (k0 + 63 > q0) {
#pragma unroll
      for (int nt = 0; nt < 4; nt++)
#pragma unroll
        for (int r = 0; r < 4; r++) {
          int qrow = q0 + quad * 4 + r;
          int key  = k0 + nt * 16 + n16;
          if (key > qrow) sacc[nt][r] = -1e30f;
        }
    }

#pragma unroll
    for (int r = 0; r < 4; r++) {
      float tmx = fmaxf(fmaxf(sacc[0][r], sacc[1][r]), fmaxf(sacc[2][r], sacc[3][r]));
#pragma unroll
      for (int d = 1; d < 16; d <<= 1) tmx = fmaxf(tmx, __shfl_xor(tmx, d));
      float nm = fmaxf(mrun[r], tmx);
      float alpha = __expf(mrun[r] - nm);
      mrun[r] = nm;
#pragma unroll
      for (int nt = 0; nt < 4; nt++) sacc[nt][r] = __expf(sacc[nt][r] - nm);
#pragma unroll
      for (int nt2 = 0; nt2 < 9; nt2++) o[nt2][r] *= alpha;
    }

#pragma unroll
    for (int nt = 0; nt < 4; nt++)
#pragma unroll
      for (int r = 0; r < 4; r++)
        P[(quad * 4 + r) * 72 + nt * 16 + n16] = (ushort_t)f2bf_bits(sacc[nt][r]);
    asm volatile("s_waitcnt lgkmcnt(0)" ::: "memory");
    s16x8 pa[2];
#pragma unroll
    for (int kseg = 0; kseg < 2; kseg++)
      pa[kseg] = *(const s16x8*)(P + n16 * 72 + kseg * 32 + quad * 8);

#pragma unroll
    for (int kseg = 0; kseg < 2; kseg++) {
#pragma unroll
      for (int ntd = 0; ntd < 8; ntd++) {
        int row = ntd * 16 + n16;
        s16x8 vf = *(const s16x8*)(VsB + row * 64 + ((kseg * 4 + quad) ^ (row & 7)) * 8);
        o[ntd] = __builtin_amdgcn_mfma_f32_16x16x32_bf16(pa[kseg], vf, o[ntd], 0, 0, 0);
      }
      o[8] = __builtin_amdgcn_mfma_f32_16x16x32_bf16(pa[kseg], ones, o[8], 0, 0, 0);
    }

    if (i == tripsA - 1) {
#pragma unroll
      for (int r = 0; r < 4; r++) {
        float lsum = __shfl(o[8][r], l & 48);
        float inv = 1.0f / lsum;
        int qrow = q0A + quad * 4 + r;
#pragma unroll
        for (int ntd = 0; ntd < 8; ntd++)
          Out[(size_t)qrow * HID + h * HD + ntd * 16 + n16] = (ushort_t)f2bf_bits(o[ntd][r] * inv);
      }
#pragma unroll
      for (int nt2 = 0; nt2 < 9; nt2++) o[nt2] = (f32x4){0.f, 0.f, 0.f, 0.f};
#pragma unroll
      for (int r = 0; r < 4; r++) mrun[r] = -1e30f;
    }
  }

#pragma unroll
  for (int r = 0; r < 4; r++) {
    float lsum = __shfl(o[8][r], l & 48);
    float inv = 1.0f / lsum;
    int qrow = q0B + quad * 4 + r;
#pragma unroll
    for (int ntd = 0; ntd < 8; ntd++)
      Out[(size_t)qrow * HID + h * HD + ntd * 16 + n16] = (ushort_t)f2bf_bits(o[ntd][r] * inv);
  }
}

extern "C" void kernel_launch(void* const* d_in, const int* in_sizes, int n_in,
                              void* d_out, int out_size, void* d_ws, size_t ws_size,
                              hipStream_t stream) {
  const float* hidden = (const float*)d_in[0];
  const float* w_qkv  = (const float*)d_in[1];
  const float* w_o    = (const float*)d_in[2];
  float* out = (float*)d_out;
  char* ws = (char*)d_ws;

  // ws layout (96 MB peak, sequential-stream aliasing):
  ushort_t* hidden_bf = (ushort_t*)ws;                   // [2048][4096] bf16, dead after gemm1
  ushort_t* Qb        = (ushort_t*)ws;                   // aliases hidden_bf
  ushort_t* wqkv_bf   = (ushort_t*)(ws + 16777216);      // [6144][4096] bf16, dead after gemm1
  ushort_t* wo_bf     = (ushort_t*)(ws + 16777216);      // aliases wqkv_bf (written after gemm1)
  ushort_t* qkv       = (ushort_t*)(ws + 67108864);      // [2048][6144] bf16, dead after rope+vt
  ushort_t* attn_out  = (ushort_t*)(ws + 67108864);      // aliases qkv
  ushort_t* Kb        = (ushort_t*)(ws + 92274688);      // [8][2048][128] bf16
  ushort_t* Vtb       = (ushort_t*)(ws + 96468992);      // [8][128][2048] bf16

  cvt_hw<<<dim3(16384), 256, 0, stream>>>(hidden, w_qkv, hidden_bf, wqkv_bf);
  // 256x256 tile: 8x24 = 192 blocks (75% CU fill, best for N=6144)
  gemm_ring<256, false><<<dim3(8, 24), 512, 0, stream>>>(hidden_bf, wqkv_bf, (void*)qkv, 2048, 6144, 4096);
  rope_vt_cvtwo<<<dim3(10752), 256, 0, stream>>>(qkv, Qb, Kb, Vtb, w_o, wo_bf);
  attn_kernel<<<dim3(16, 32), 256, 0, stream>>>(Qb, Kb, Vtb, attn_out);
  // 128x256 tile: 16x16 = 256 blocks (100% CU fill for N=4096)
  gemm_ring<128, true><<<dim3(16, 16), 512, 0, stream>>>(attn_out, wo_bf, (void*)out, 2048, 4096, 4096);
}

// Round 3
// 560.193 us; speedup vs baseline: 1.0217x; 1.0217x over previous
//
#include <hip/hip_runtime.h>
#include <cstdint>

#define S_LEN 2048
#define HID   4096
#define NHQ   32
#define NKV   8
#define HD    128
#define QKV_N 6144

typedef float  f32x4 __attribute__((ext_vector_type(4)));
typedef short  s16x8 __attribute__((ext_vector_type(8)));
typedef unsigned short ushort_t;

typedef __attribute__((address_space(3))) void       lds_void;
typedef const __attribute__((address_space(1))) void gbl_void;

__device__ __forceinline__ void gload_lds16(const void* g, void* l) {
  __builtin_amdgcn_global_load_lds((gbl_void*)g, (lds_void*)l, 16, 0, 0);
}

__device__ __forceinline__ short f2bf_bits(float f) {
  union { __bf16 b; short s; } u;
  u.b = (__bf16)f;
  return u.s;
}
__device__ __forceinline__ float bf2f(unsigned short u) {
  union { unsigned int i; float f; } x;
  x.i = ((unsigned int)u) << 16;
  return x.f;
}

__device__ __forceinline__ void cvt8(const float* src, ushort_t* dst, int j) {
  const f32x4* s = (const f32x4*)src;
  f32x4 a = s[j * 2], b = s[j * 2 + 1];
  s16x8 r;
  r[0] = f2bf_bits(a[0]); r[1] = f2bf_bits(a[1]); r[2] = f2bf_bits(a[2]); r[3] = f2bf_bits(a[3]);
  r[4] = f2bf_bits(b[0]); r[5] = f2bf_bits(b[1]); r[6] = f2bf_bits(b[2]); r[7] = f2bf_bits(b[3]);
  *((s16x8*)dst + j) = r;
}

// ---------------- fused cvt: hidden (1048576 vec8) + w_qkv (3145728 vec8) ----------------
__global__ __launch_bounds__(256)
void cvt_hw(const float* __restrict__ h, const float* __restrict__ wq,
            ushort_t* __restrict__ hb, ushort_t* __restrict__ wqb) {
  int i = blockIdx.x * 256 + threadIdx.x;
  if (i < 1048576) cvt8(h, hb, i);
  else             cvt8(wq, wqb, i - 1048576);
}

// ---------------- counted-vmcnt waits ----------------
template <int N> __device__ __forceinline__ void wait_vm() {
  if constexpr (N == 6)      asm volatile("s_waitcnt vmcnt(6)" ::: "memory");
  else if constexpr (N == 4) asm volatile("s_waitcnt vmcnt(4)" ::: "memory");
  else                       asm volatile("s_waitcnt vmcnt(0)" ::: "memory");
}

// ---------------- 8-phase 256x256 bf16 GEMM (m201-style), C = A * B^T ----------------
// 512 thr = 8 waves. Wave covers rows {wm*64..+63, 128+wm*64..+63}, cols {wn*32..+31,
// 128+wn*32..+31}. Phase (qm,qn) computes one quadrant: reads ONLY A-half qm, B-half qn.
// K-tile BK=64 stored as two BK=32 slices (chunk-XOR layout: chunk c of row r holds
// kseg c^(r&3); frag read = dense 1KB, conflict-free). 2 K-tile buffers.
// Per phase: ds_read frags -> 16 MFMA (setprio) -> stage ONE half-tile (2 gload_lds)
// -> vmcnt(6) -> raw s_barrier. Stage schedule (WAR lag>=1 phase behind last reader's
// barrier; RAW slack>=3 phases vs vmcnt(6) retirement):
//  ph1:A1(t+1)->b1  ph2:B1(t+1)->b1  ph3:A0(t+2)->b0  ph4:B0(t+2)->b0
//  ph5:A1(t+2)->b0  ph6:B1(t+2)->b0  ph7:A0(t+3)->b1  ph8:B0(t+3)->b1
// Final iteration: ph3-8 stages skipped; counted wait then vacuous, so ph4 drains
// vmcnt(0) once (covers ph1/ph2 loads read at ph6-8).
template <bool OUTF32>
__global__ __launch_bounds__(512, 2)
void gemm8p(const ushort_t* __restrict__ Ag, const ushort_t* __restrict__ Bg,
            void* __restrict__ Cp, int M, int N, int K) {
  __shared__ __align__(16) ushort_t As[2][2][256 * 32];  // [buf][ksub] 64 KB
  __shared__ __align__(16) ushort_t Bs[2][2][256 * 32];  // 64 KB

  const int t = threadIdx.x;
  const int w = t >> 6, l = t & 63;
  const int n16 = l & 15, quad = l >> 4;
  const int wm = w >> 2, wn = w & 3;
  const int sw16 = (quad ^ (n16 & 3)) * 16;
  const int m0 = blockIdx.x * 256, n0 = blockIdx.y * 256;

  // staging: per half-tile (128 rows x 64 k), thread t covers row h*128+(t>>2),
  // chunk t&3, swizzled kseg (t&3)^(row&3); LDS dest linear in lane (base + t*16).
  const int srow = t >> 2;
  const int schunk = (t & 3) ^ (srow & 3);
  const ushort_t* Abase = Ag + (size_t)(m0 + srow) * K + schunk * 8;
  const ushort_t* Bbase = Bg + (size_t)(n0 + srow) * K + schunk * 8;
  char* AsB = (char*)&As[0][0][0];
  char* BsB = (char*)&Bs[0][0][0];
  const size_t hstep = (size_t)128 * K;

  auto stageA = [&](int b, int h, int tile) {
    const ushort_t* g = Abase + (size_t)h * hstep + tile * 64;
    gload_lds16(g,      AsB + b * 32768 + h * 8192 + t * 16);
    gload_lds16(g + 32, AsB + b * 32768 + 16384 + h * 8192 + t * 16);
  };
  auto stageB = [&](int b, int h, int tile) {
    const ushort_t* g = Bbase + (size_t)h * hstep + tile * 64;
    gload_lds16(g,      BsB + b * 32768 + h * 8192 + t * 16);
    gload_lds16(g + 32, BsB + b * 32768 + 16384 + h * 8192 + t * 16);
  };

  const int aRowBase = wm * 64 + n16;
  const int bRowBase = wn * 32 + n16;
  const char* AsR = (const char*)AsB;
  const char* BsR = (const char*)BsB;

  f32x4 acc[8][4] = {};
  s16x8 af[4][2];

#define PHASE(b, qm, qn, STAGE, WZ) do {                                            \
    if ((qn) == 0) {                                                                \
      _Pragma("unroll")                                                             \
      for (int mf = 0; mf < 4; mf++)                                                \
        _Pragma("unroll")                                                           \
        for (int ks = 0; ks < 2; ks++)                                              \
          af[mf][ks] = *(const s16x8*)(AsR + (b) * 32768 + ks * 16384 +             \
                        ((qm) * 128 + mf * 16 + aRowBase) * 64 + sw16);             \
    }                                                                               \
    s16x8 bf[2][2];                                                                 \
    _Pragma("unroll")                                                               \
    for (int nf = 0; nf < 2; nf++)                                                  \
      _Pragma("unroll")                                                             \
      for (int ks = 0; ks < 2; ks++)                                                \
        bf[nf][ks] = *(const s16x8*)(BsR + (b) * 32768 + ks * 16384 +               \
                      ((qn) * 128 + nf * 16 + bRowBase) * 64 + sw16);               \
    __builtin_amdgcn_s_setprio(1);                                                  \
    _Pragma("unroll")                                                               \
    for (int ks = 0; ks < 2; ks++)                                                  \
      _Pragma("unroll")                                                             \
      for (int mf = 0; mf < 4; mf++)                                                \
        _Pragma("unroll")                                                           \
        for (int nf = 0; nf < 2; nf++)                                              \
          acc[(qm) * 4 + mf][(qn) * 2 + nf] = __builtin_amdgcn_mfma_f32_16x16x32_bf16( \
              af[mf][ks], bf[nf][ks], acc[(qm) * 4 + mf][(qn) * 2 + nf], 0, 0, 0);  \
    __builtin_amdgcn_s_setprio(0);                                                  \
    STAGE;                                                                          \
    if (WZ) wait_vm<0>(); else wait_vm<6>();                                        \
    asm volatile("" ::: "memory");                                                  \
    __builtin_amdgcn_s_barrier();                                                   \
    asm volatile("" ::: "memory");                                                  \
  } while (0)

  const int NT = K >> 6;   // K-tiles (64 for K=4096)
  const int NI = NT >> 1;  // iterations

  // Prologue: tile0 fully (8 loads) + tile1 A0,B0 (4 loads); drain tile0 only.
  stageA(0, 0, 0); stageA(0, 1, 0); stageB(0, 0, 0); stageB(0, 1, 0);
  stageA(1, 0, 1); stageB(1, 0, 1);
  wait_vm<4>();
  asm volatile("" ::: "memory");
  __builtin_amdgcn_s_barrier();
  asm volatile("" ::: "memory");

  for (int i = 0; i < NI - 1; i++) {
    const int tp1 = 2 * i + 1, tp2 = 2 * i + 2, tp3 = 2 * i + 3;
    PHASE(0, 0, 0, stageA(1, 1, tp1), 0);
    PHASE(0, 0, 1, stageB(1, 1, tp1), 0);
    PHASE(0, 1, 0, stageA(0, 0, tp2), 0);
    PHASE(0, 1, 1, stageB(0, 0, tp2), 0);
    PHASE(1, 0, 0, stageA(0, 1, tp2), 0);
    PHASE(1, 0, 1, stageB(0, 1, tp2), 0);
    PHASE(1, 1, 0, stageA(1, 0, tp3), 0);
    PHASE(1, 1, 1, stageB(1, 0, tp3), 0);
  }
  // Final iteration (tile NT-2 / NT-1): only tile NT-1's A1,B1 remain to stage.
  PHASE(0, 0, 0, stageA(1, 1, NT - 1), 0);
  PHASE(0, 0, 1, stageB(1, 1, NT - 1), 0);
  PHASE(0, 1, 0, ((void)0), 0);
  PHASE(0, 1, 1, ((void)0), 1);
  PHASE(1, 0, 0, ((void)0), 1);
  PHASE(1, 0, 1, ((void)0), 1);
  PHASE(1, 1, 0, ((void)0), 1);
  PHASE(1, 1, 1, ((void)0), 1);
#undef PHASE

#pragma unroll
  for (int a = 0; a < 8; a++)
#pragma unroll
    for (int bq = 0; bq < 4; bq++)
#pragma unroll
      for (int r = 0; r < 4; r++) {
        int row = m0 + (a >> 2) * 128 + wm * 64 + (a & 3) * 16 + quad * 4 + r;
        int col = n0 + (bq >> 1) * 128 + wn * 32 + (bq & 1) * 16 + n16;
        float v = acc[a][bq][r];
        if constexpr (OUTF32) ((float*)Cp)[(size_t)row * N + col] = v;
        else ((ushort_t*)Cp)[(size_t)row * N + col] = (ushort_t)f2bf_bits(v);
      }
}

// ---------------- fused mid-pipeline: RoPE scatter + V-transpose + cvt(w_o) ----------------
// blocks [0,2048): rope row s; [2048,2560): v_transpose; [2560,10752): w_o cvt.
__global__ __launch_bounds__(256)
void rope_vt_cvtwo(const ushort_t* __restrict__ qkv, ushort_t* __restrict__ Q,
                   ushort_t* __restrict__ Kc, ushort_t* __restrict__ Vt,
                   const float* __restrict__ wo, ushort_t* __restrict__ wob) {
  __shared__ __align__(16) ushort_t tile[64][72];
  const int b = blockIdx.x;
  const int t = threadIdx.x;
  if (b < 2048) {
    const int s = b;
    const float LN1E4_64 = 0.14391156831212787f;  // ln(10000)/64
    for (int item = t; item < (NHQ + NKV) * 64; item += 256) {
      int head = item >> 6, i = item & 63;
      float f = expf(-(float)i * LN1E4_64);
      float ang = (float)s * f;
      float sn, cs;
      sincosf(ang, &sn, &cs);
      if (head < NHQ) {
        const ushort_t* src = qkv + (size_t)s * QKV_N + head * HD;
        float x1 = bf2f(src[i]), x2 = bf2f(src[64 + i]);
        const float sc = 0.08838834764831845f;  // 1/sqrt(128)
        ushort_t* dst = Q + ((size_t)head * S_LEN + s) * HD;
        dst[i]      = (ushort_t)f2bf_bits((x1 * cs - x2 * sn) * sc);
        dst[64 + i] = (ushort_t)f2bf_bits((x1 * sn + x2 * cs) * sc);
      } else {
        int kv = head - NHQ;
        const ushort_t* src = qkv + (size_t)s * QKV_N + 4096 + kv * HD;
        float x1 = bf2f(src[i]), x2 = bf2f(src[64 + i]);
        ushort_t* dst = Kc + ((size_t)kv * S_LEN + s) * HD;
        dst[i]      = (ushort_t)f2bf_bits(x1 * cs - x2 * sn);
        dst[64 + i] = (ushort_t)f2bf_bits(x1 * sn + x2 * cs);
      }
    }
  } else if (b < 2560) {
    const int bb = b - 2048;
    const int s0 = (bb & 31) * 64;
    const int by = bb >> 5;
    const int kv = by >> 1;
    const int d0 = (by & 1) * 64;
    {
      int r = t >> 2, c = (t & 3) * 16;
      const ushort_t* src = qkv + (size_t)(s0 + r) * QKV_N + 5120 + kv * HD + d0 + c;
      *(s16x8*)&tile[r][c]     = *(const s16x8*)src;
      *(s16x8*)&tile[r][c + 8] = *(const s16x8*)(src + 8);
    }
    __syncthreads();
    {
      int d = t >> 2, sseg = (t & 3) * 16;
      ushort_t* dst = Vt + ((size_t)kv * HD + d0 + d) * S_LEN + s0 + sseg;
      s16x8 o1, o2;
#pragma unroll
      for (int i = 0; i < 8; i++) { o1[i] = tile[sseg + i][d]; o2[i] = tile[sseg + 8 + i][d]; }
      *(s16x8*)dst = o1;
      *(s16x8*)(dst + 8) = o2;
    }
  } else {
    int j = (b - 2560) * 256 + t;  // 2097152 vec8 of w_o
    cvt8(wo, wob, j);
  }
}

// ---------------- Flash attention (unchanged) ----------------
__global__ __launch_bounds__(256)
void attn_kernel(const ushort_t* __restrict__ Q, const ushort_t* __restrict__ Kc,
                 const ushort_t* __restrict__ Vt, ushort_t* __restrict__ Out) {
  __shared__ __align__(16) ushort_t Ks[2][64 * 128];   // 32 KB
  __shared__ __align__(16) ushort_t Vs[2][128 * 64];   // 32 KB
  __shared__ __align__(16) ushort_t Pl[4][16 * 72];    // 9 KB
  const int bx = blockIdx.x;                            // 0..15
  const int h = blockIdx.y;
  const int t = threadIdx.x, w = t >> 6, l = t & 63;
  const int n16 = l & 15, quad = l >> 4;
  const int kv = h >> 2;
  const ushort_t* Qh = Q  + (size_t)h  * S_LEN * HD;
  const ushort_t* Kh = Kc + (size_t)kv * S_LEN * HD;
  const ushort_t* Vh = Vt + (size_t)kv * HD * S_LEN;

  const int qtA = bx, qtB = 31 - bx;
  const int q0A = qtA * 64 + w * 16, q0B = qtB * 64 + w * 16;
  const int tripsA = qtA + 1;
  const int TOTAL = 33;

  s16x8 qfA[4], qfB[4];
#pragma unroll
  for (int ks = 0; ks < 4; ks++) {
    qfA[ks] = *(const s16x8*)(Qh + (size_t)(q0A + n16) * HD + ks * 32 + quad * 8);
    qfB[ks] = *(const s16x8*)(Qh + (size_t)(q0B + n16) * HD + ks * 32 + quad * 8);
  }

  s16x8 ones;
  {
    short v = (n16 == 0) ? (short)0x3F80 : (short)0;
#pragma unroll
    for (int j = 0; j < 8; j++) ones[j] = v;
  }

  f32x4 o[9] = {};
  float mrun[4] = {-1e30f, -1e30f, -1e30f, -1e30f};

  ushort_t* P = Pl[w];

  auto stage = [&](int k0, int buf) {
#pragma unroll
    for (int c = 0; c < 4; c++) {
      int idx = (c * 4 + w) * 64 + l;
      int row = idx >> 4, sc = idx & 15;
      int dseg = sc ^ (row & 15);
      gload_lds16(Kh + (size_t)(k0 + row) * HD + dseg * 8,
                  (char*)&Ks[buf][0] + (c * 4 + w) * 1024);
    }
#pragma unroll
    for (int c = 0; c < 4; c++) {
      int idx = (c * 4 + w) * 64 + l;
      int row = idx >> 3, sc = idx & 7;
      int ks2 = sc ^ (row & 7);
      gload_lds16(Vh + (size_t)row * S_LEN + k0 + ks2 * 8,
                  (char*)&Vs[buf][0] + (c * 4 + w) * 1024);
    }
  };

  stage(0, 0);

  for (int i = 0; i < TOTAL; i++) {
    const bool isA = (i < tripsA);
    const int kt = isA ? i : i - tripsA;
    const int q0 = isA ? q0A : q0B;
    const int k0 = kt * 64;
    const int buf = i & 1;

    __syncthreads();

    if (i + 1 < TOTAL) {
      const bool nA = (i + 1 < tripsA);
      const int nkt = nA ? (i + 1) : (i + 1 - tripsA);
      stage(nkt * 64, buf ^ 1);
    }

    const ushort_t* KsB = &Ks[buf][0];
    const ushort_t* VsB = &Vs[buf][0];

    f32x4 sacc[4] = {};
#pragma unroll
    for (int ks = 0; ks < 4; ks++) {
      s16x8 qf = isA ? qfA[ks] : qfB[ks];
#pragma unroll
      for (int nt = 0; nt < 4; nt++) {
        int row = nt * 16 + n16;
        s16x8 kf = *(const s16x8*)(KsB + row * 128 + ((ks * 4 + quad) ^ (row & 15)) * 8);
        sacc[nt] = __builtin_amdgcn_mfma_f32_16x16x32_bf16(qf, kf, sacc[nt], 0, 0, 0);
      }
    }

    if (k0 + 63 > q0) {
#pragma unroll
      for (int nt = 0; nt < 4; nt++)
#pragma unroll
        for (int r = 0; r < 4; r++) {
          int qrow = q0 + quad * 4 + r;
          int key  = k0 + nt * 16 + n16;
          if (key > qrow) sacc[nt][r] = -1e30f;
        }
    }

#pragma unroll
    for (int r = 0; r < 4; r++) {
      float tmx = fmaxf(fmaxf(sacc[0][r], sacc[1][r]), fmaxf(sacc[2][r], sacc[3][r]));
#pragma unroll
      for (int d = 1; d < 16; d <<= 1) tmx = fmaxf(tmx, __shfl_xor(tmx, d));
      float nm = fmaxf(mrun[r], tmx);
      float alpha = __expf(mrun[r] - nm);
      mrun[r] = nm;
#pragma unroll
      for (int nt = 0; nt < 4; nt++) sacc[nt][r] = __expf(sacc[nt][r] - nm);
#pragma unroll
      for (int nt2 = 0; nt2 < 9; nt2++) o[nt2][r] *= alpha;
    }

#pragma unroll
    for (int nt = 0; nt < 4; nt++)
#pragma unroll
      for (int r = 0; r < 4; r++)
        P[(quad * 4 + r) * 72 + nt * 16 + n16] = (ushort_t)f2bf_bits(sacc[nt][r]);
    asm volatile("s_waitcnt lgkmcnt(0)" ::: "memory");
    s16x8 pa[2];
#pragma unroll
    for (int kseg = 0; kseg < 2; kseg++)
      pa[kseg] = *(const s16x8*)(P + n16 * 72 + kseg * 32 + quad * 8);

#pragma unroll
    for (int kseg = 0; kseg < 2; kseg++) {
#pragma unroll
      for (int ntd = 0; ntd < 8; ntd++) {
        int row = ntd * 16 + n16;
        s16x8 vf = *(const s16x8*)(VsB + row * 64 + ((kseg * 4 + quad) ^ (row & 7)) * 8);
        o[ntd] = __builtin_amdgcn_mfma_f32_16x16x32_bf16(pa[kseg], vf, o[ntd], 0, 0, 0);
      }
      o[8] = __builtin_amdgcn_mfma_f32_16x16x32_bf16(pa[kseg], ones, o[8], 0, 0, 0);
    }

    if (i == tripsA - 1) {
#pragma unroll
      for (int r = 0; r < 4; r++) {
        float lsum = __shfl(o[8][r], l & 48);
        float inv = 1.0f / lsum;
        int qrow = q0A + quad * 4 + r;
#pragma unroll
        for (int ntd = 0; ntd < 8; ntd++)
          Out[(size_t)qrow * HID + h * HD + ntd * 16 + n16] = (ushort_t)f2bf_bits(o[ntd][r] * inv);
      }
#pragma unroll
      for (int nt2 = 0; nt2 < 9; nt2++) o[nt2] = (f32x4){0.f, 0.f, 0.f, 0.f};
#pragma unroll
      for (int r = 0; r < 4; r++) mrun[r] = -1e30f;
    }
  }

#pragma unroll
  for (int r = 0; r < 4; r++) {
    float lsum = __shfl(o[8][r], l & 48);
    float inv = 1.0f / lsum;
    int qrow = q0B + quad * 4 + r;
#pragma unroll
    for (int ntd = 0; ntd < 8; ntd++)
      Out[(size_t)qrow * HID + h * HD + ntd * 16 + n16] = (ushort_t)f2bf_bits(o[ntd][r] * inv);
  }
}

extern "C" void kernel_launch(void* const* d_in, const int* in_sizes, int n_in,
                              void* d_out, int out_size, void* d_ws, size_t ws_size,
                              hipStream_t stream) {
  const float* hidden = (const float*)d_in[0];
  const float* w_qkv  = (const float*)d_in[1];
  const float* w_o    = (const float*)d_in[2];
  float* out = (float*)d_out;
  char* ws = (char*)d_ws;

  // ws layout (96 MB peak, sequential-stream aliasing):
  ushort_t* hidden_bf = (ushort_t*)ws;                   // [2048][4096] bf16, dead after gemm1
  ushort_t* Qb        = (ushort_t*)ws;                   // aliases hidden_bf
  ushort_t* wqkv_bf   = (ushort_t*)(ws + 16777216);      // [6144][4096] bf16, dead after gemm1
  ushort_t* wo_bf     = (ushort_t*)(ws + 16777216);      // aliases wqkv_bf (written after gemm1)
  ushort_t* qkv       = (ushort_t*)(ws + 67108864);      // [2048][6144] bf16, dead after rope+vt
  ushort_t* attn_out  = (ushort_t*)(ws + 67108864);      // aliases qkv
  ushort_t* Kb        = (ushort_t*)(ws + 92274688);      // [8][2048][128] bf16
  ushort_t* Vtb       = (ushort_t*)(ws + 96468992);      // [8][128][2048] bf16

  cvt_hw<<<dim3(16384), 256, 0, stream>>>(hidden, w_qkv, hidden_bf, wqkv_bf);
  // 256x256 tiles: 8x24 = 192 blocks (1/CU, 8-phase template regime)
  gemm8p<false><<<dim3(8, 24), 512, 0, stream>>>(hidden_bf, wqkv_bf, (void*)qkv, 2048, 6144, 4096);
  rope_vt_cvtwo<<<dim3(10752), 256, 0, stream>>>(qkv, Qb, Kb, Vtb, w_o, wo_bf);
  attn_kernel<<<dim3(16, 32), 256, 0, stream>>>(Qb, Kb, Vtb, attn_out);
  // 8x16 = 128 blocks (50% CU fill, per-block time ~= gemm1's)
  gemm8p<true><<<dim3(8, 16), 512, 0, stream>>>(attn_out, wo_bf, (void*)out, 2048, 4096, 4096);
}